// Round 1
// 80.947 us; speedup vs baseline: 1.0250x; 1.0250x over previous
//
#include <hip/hip_runtime.h>
#include <math.h>

#define NMAX   64
#define NSITES 12
#define SPLIT  4      // threads per batch element (3 sites each)
#define BLOCK  256
#define RS     68     // LDS row stride (floats): rows 16B-aligned; the 4
                      // site rows read per wave-op start at banks
                      // {0,12,24,4} -> disjoint b128 spans, conflict-free

#define B_SOFT 0.01f
#define PAD_C  4.0e4f   // sentinel coord -> r2 ~ 3e9 -> clamped -> f ~ 1e-8
#define R2_MAX 248.0f   // bits 0x43780000 -> last bin (entry 767)
#define TBL_LO 1392     // (bits >> 19) of 2^-40
#define TBL_N  768      // bins 1392..2159, 16 per octave, 48 octaves

#define NB_FLOATS  (NSITES * RS)          // 816 floats per coord array
// LDS overlay: neighbor arrays live in [0, 6528); table lives at byte
// offset TBL_LO*8 = 11136 so the gather address is (bits>>16)&~7 directly
// (no idx-subtract, no clamp-to-0, no lshl_add).
#define TBL_OFF    (TBL_LO * 8)           // 11136
#define SMEM_BYTES (TBL_OFF + TBL_N * 8)  // 17280 -> 8 blocks/CU = 138 KiB

// Device-global scratch filled by init_kernel each launch (d_ws is poisoned
// by the harness, and a static global avoids any ws_size assumption).
// layout (floats): [0,816) nbx | [816,1632) nby | [1664,3200) table (c,s)
#define WS_TBL_F   1664
#define WS_FLOATS  3200
__device__ __align__(16) float g_ws[WS_FLOATS];
__device__ int g_m;

typedef float v2f __attribute__((ext_vector_type(2)));
typedef float v4f __attribute__((ext_vector_type(4)));

// f(r2) = exp(-sqrt(r2)) / (sqrt(r2) + b), exact (init kernel only)
__device__ __forceinline__ float f_exact(float r2) {
    const float r = sqrtf(r2);
    return expf(-r) / (r + B_SOFT);
}

// One block: compact neighbor lists + build the piecewise-linear table ONCE
// (was redundantly rebuilt by all 2048 blocks: ~3.6 us of expf chains).
__global__ void init_kernel(const float* __restrict__ neighbors,
                            const float* __restrict__ mask) {
    __shared__ int cnt[NSITES];
    const int tid  = threadIdx.x;
    const int wv   = tid >> 6;
    const int lane = tid & 63;

    // Sentinel fill: slots past a site's count give r2~3e9 -> clamped ->
    // f ~ 1e-8 each (negligible).
    for (int i = tid; i < 2 * NB_FLOATS; i += BLOCK) g_ws[i] = PAD_C;
    __syncthreads();

    // Ballot-compaction of neighbor lists into SoA (~64 -> ~58).
    for (int s = wv; s < NSITES; s += 4) {
        const bool keep = mask[s * NMAX + lane] > 0.5f;
        const unsigned long long bal = __ballot(keep);
        if (keep) {
            const int pos = __popcll(bal & ((1ull << lane) - 1ull));
            const float2 p = ((const float2*)neighbors)[s * NMAX + lane];
            g_ws[s * RS + pos]             = p.x;
            g_ws[NB_FLOATS + s * RS + pos] = p.y;
        }
        if (lane == 0) cnt[s] = __popcll(bal);
    }
    __syncthreads();
    if (tid == 0) {
        int m = 0;
        #pragma unroll
        for (int s = 0; s < NSITES; ++s) m = max(m, cnt[s]);
        g_m = (m + 3) & ~3;   // <= 64, RS-safe
    }

    // Piecewise-linear table: bin i covers r2 in
    // [bitcast((i+LO)<<19), bitcast((i+LO+1)<<19)); chord + midpoint corr.
    for (int i = tid; i < TBL_N; i += BLOCK) {
        const unsigned ii = (unsigned)(i + TBL_LO);
        const float b0 = __builtin_bit_cast(float, ii << 19);
        const float b1 = __builtin_bit_cast(float, (ii + 1u) << 19);
        const float f0 = f_exact(b0);
        const float f1 = f_exact(b1);
        const float fm = f_exact(0.5f * (b0 + b1));
        const float sl = (f1 - f0) / (b1 - b0);
        const float c  = f0 - sl * b0 - 0.5f * (0.5f * (f0 + f1) - fm);
        g_ws[WS_TBL_F + 2 * i]     = c;
        g_ws[WS_TBL_F + 2 * i + 1] = sl;
    }
}

__global__ __launch_bounds__(BLOCK, 8)
void pot_energy_kernel(const float* __restrict__ x,
                       float* __restrict__ out, int B) {
    __shared__ __align__(16) char smem[SMEM_BYTES];
    const int tid = threadIdx.x;

    // Lean prologue: copy precomputed data from L2-hot device global.
    {
        const float4* s0 = (const float4*)g_ws;             // nbx+nby: 408 f4
        float4* d0 = (float4*)smem;
        #pragma unroll
        for (int i = 0; i < 2; ++i) {
            const int idx = tid + i * BLOCK;
            if (idx < (2 * NB_FLOATS) / 4) d0[idx] = s0[idx];
        }
        const float4* s1 = (const float4*)(g_ws + WS_TBL_F); // table: 384 f4
        float4* d1 = (float4*)(smem + TBL_OFF);
        #pragma unroll
        for (int i = 0; i < 2; ++i) {
            const int idx = tid + i * BLOCK;
            if (idx < (TBL_N * 8) / 16) d1[idx] = s1[idx];
        }
    }
    const int m = g_m;          // uniform -> scalar load
    __syncthreads();

    const int gtid = blockIdx.x * BLOCK + tid;
    const int e = gtid >> 2;
    const int q = gtid & 3;
    if (e >= B) return;

    const float2* xp = (const float2*)(x + (size_t)gtid * 6);
    const float2 p0 = xp[0], p1 = xp[1], p2 = xp[2];
    const float xs_[3] = { p0.x, p1.x, p2.x };
    const float ys_[3] = { p0.y, p1.y, p2.y };

    const float R2MINF = __builtin_bit_cast(float, 0x2B800000u);  // 2^-40

    float accC = 0.f, accS = 0.f;   // sum(c_i) and sum(s_i * r2_i)
    #pragma unroll
    for (int s = 0; s < 3; ++s) {
        const int site = q * 3 + s;
        const float* __restrict__ rx = (const float*)smem + site * RS;
        const float* __restrict__ ry = rx + NB_FLOATS;
        const v2f xs2 = { xs_[s], xs_[s] };
        const v2f ys2 = { ys_[s], ys_[s] };
        #pragma unroll 2
        for (int j0 = 0; j0 < m; j0 += 4) {
            const v4f nx4 = *(const v4f*)(rx + j0);   // ds_read_b128, bcast
            const v4f ny4 = *(const v4f*)(ry + j0);
            // r2 via packed f32 (v_pk_add/mul/fma on gfx950): 4 pk-ops per
            // 2 interactions; falls back to identical scalar count if the
            // backend scalarizes.
            const v2f dxA = xs2 - nx4.xy;
            const v2f dxB = xs2 - nx4.zw;
            const v2f dyA = ys2 - ny4.xy;
            const v2f dyB = ys2 - ny4.zw;
            const v2f r2A = __builtin_elementwise_fma(dyA, dyA, dxA * dxA);
            const v2f r2B = __builtin_elementwise_fma(dyB, dyB, dxB * dxB);
            const float r2k[4] = { r2A.x, r2A.y, r2B.x, r2B.y };
            #pragma unroll
            for (int k = 0; k < 4; ++k) {
                // single med3 clamps both ends (catches sentinels AND tiny r2)
                const float r2c = __builtin_amdgcn_fmed3f(r2k[k], R2MINF, R2_MAX);
                // table overlay: byte offset = (bits>>19)*8, no bias/clamp ops
                const unsigned off =
                    (__builtin_bit_cast(unsigned, r2c) >> 16) & 0xFFF8u;
                const float2 cs = *(const float2*)(smem + off);  // ds_read_b64
                accC += cs.x;
                accS = fmaf(cs.y, r2c, accS);
            }
        }
    }

    float acc = accC + accS;
    acc += __shfl_xor(acc, 1);   // combine the 4 partials of element e
    acc += __shfl_xor(acc, 2);
    if (q == 0) out[e] = acc;
}

extern "C" void kernel_launch(void* const* d_in, const int* in_sizes, int n_in,
                              void* d_out, int out_size, void* d_ws, size_t ws_size,
                              hipStream_t stream) {
    const float* x   = (const float*)d_in[0];
    const float* nbr = (const float*)d_in[1];
    const float* msk = (const float*)d_in[2];
    float* out = (float*)d_out;

    const int B = in_sizes[0] / 24;

    init_kernel<<<1, BLOCK, 0, stream>>>(nbr, msk);

    const int total_threads = B * SPLIT;
    const int blocks = (total_threads + BLOCK - 1) / BLOCK;
    pot_energy_kernel<<<blocks, BLOCK, 0, stream>>>(x, out, B);
}